// Round 3
// baseline (205.735 us; speedup 1.0000x reference)
//
#include <hip/hip_runtime.h>

#define BB 8
#define NN 4096
#define TPB 512
#define WAVES 8
#define RPW 4                    // rows per wave
#define TI (WAVES * RPW)         // 32 rows per block
#define NRB (NN / TI)            // 128 row-blocks per batch
#define NGRP (NN / 256)          // 16 column groups of 256 cols

// ws layout (floats):
//   q:     [BB*NN*3]                 offset 0
//   neigh: [BB*NN*3]                 offset 98304
//   degp:  [BB*NRB*NN] (or [BB*NN])  offset 196608
// partial mode total ~17.6 MB

__global__ __launch_bounds__(256) void k_init(const float* __restrict__ p1,
                                              const float* __restrict__ p2,
                                              float* __restrict__ q,
                                              float* __restrict__ deg_atomic,
                                              float* __restrict__ out,
                                              int atomic_mode) {
    int i = blockIdx.x * 256 + threadIdx.x;
    if (i < BB * NN * 3) q[i] = p2[i] - p1[i];
    if (atomic_mode && i < BB * NN) deg_atomic[i] = 0.0f;
    if (i == 0) out[0] = 0.0f;
}

__global__ __launch_bounds__(TPB, 6) void k_main(const float* __restrict__ A,
                                                 const float* __restrict__ q,
                                                 float* __restrict__ neigh,
                                                 float* __restrict__ degp,
                                                 int atomic_mode) {
    // deg accumulator, layout [comp jj][col>>2]: lane l of any wave hits
    // address (g*64+l) per component -> banks 2-way aliased, conflict-free
    __shared__ float dlds[NN];   // 16 KiB

    const int tid  = threadIdx.x;
    const int lane = tid & 63;
    const int w    = tid >> 6;
    const int b    = blockIdx.x / NRB;
    const int rb   = blockIdx.x % NRB;
    const int ro   = rb * TI + w * RPW;   // this wave's first row

#pragma unroll
    for (int k = 0; k < NN / TPB; ++k) dlds[tid + k * TPB] = 0.0f;
    __syncthreads();

    const float* Ab = A + (size_t)b * NN * NN;
    const float* qb = q + (size_t)b * NN * 3;

    float nacc[RPW][3];
#pragma unroll
    for (int r = 0; r < RPW; ++r) {
        nacc[r][0] = 0.0f; nacc[r][1] = 0.0f; nacc[r][2] = 0.0f;
    }

    for (int g = 0; g < NGRP; ++g) {
        const int jc = g * 256 + lane * 4;   // this lane's 4 columns
        const float4 q0 = *(const float4*)(qb + (size_t)jc * 3);
        const float4 q1 = *(const float4*)(qb + (size_t)jc * 3 + 4);
        const float4 q2 = *(const float4*)(qb + (size_t)jc * 3 + 8);
        // col0=(q0.x,q0.y,q0.z) col1=(q0.w,q1.x,q1.y) col2=(q1.z,q1.w,q2.x) col3=(q2.y,q2.z,q2.w)

        float dg0 = 0.f, dg1 = 0.f, dg2 = 0.f, dg3 = 0.f;
#pragma unroll
        for (int r = 0; r < RPW; ++r) {
            const float4 a = *(const float4*)(Ab + (size_t)(ro + r) * NN + jc);
            dg0 += a.x; dg1 += a.y; dg2 += a.z; dg3 += a.w;
            nacc[r][0] += a.x * q0.x + a.y * q0.w + a.z * q1.z + a.w * q2.y;
            nacc[r][1] += a.x * q0.y + a.y * q1.x + a.z * q1.w + a.w * q2.z;
            nacc[r][2] += a.x * q0.z + a.y * q1.y + a.z * q2.x + a.w * q2.w;
        }
        const int j4 = jc >> 2;              // 0..1023
        atomicAdd(&dlds[0 * 1024 + j4], dg0);
        atomicAdd(&dlds[1 * 1024 + j4], dg1);
        atomicAdd(&dlds[2 * 1024 + j4], dg2);
        atomicAdd(&dlds[3 * 1024 + j4], dg3);
    }

    // reduce nacc (12 values) across the wave's 64 lanes
    float myval = 0.0f;
#pragma unroll
    for (int r = 0; r < RPW; ++r) {
#pragma unroll
        for (int d = 0; d < 3; ++d) {
            float v = nacc[r][d];
#pragma unroll
            for (int s = 1; s < 64; s <<= 1) v += __shfl_xor(v, s, 64);
            if (lane == r * 3 + d) myval = v;
        }
    }
    if (lane < RPW * 3) {
        neigh[((size_t)b * NN + ro) * 3 + lane] = myval;
    }

    __syncthreads();
    if (atomic_mode) {
        float* dg = degp + (size_t)b * NN;
#pragma unroll
        for (int k = 0; k < NN / TPB; ++k) {
            const int col = tid + k * TPB;
            atomicAdd(&dg[col], dlds[(col & 3) * 1024 + (col >> 2)]);
        }
    } else {
        float* dg = degp + ((size_t)b * NRB + rb) * NN;
#pragma unroll
        for (int k = 0; k < NN / TPB; ++k) {
            const int col = tid + k * TPB;
            dg[col] = dlds[(col & 3) * 1024 + (col >> 2)];
        }
    }
}

// 512 blocks x 256 threads; block handles 64 rows, each of the 4 waves sums a
// quarter of the slabs, LDS-combine, then wave 0 finishes the loss.
__global__ __launch_bounds__(256) void k_final(const float* __restrict__ q,
                                               const float* __restrict__ neigh,
                                               const float* __restrict__ degp,
                                               int nslab,
                                               float* __restrict__ out) {
    __shared__ float dred[4][64];
    const int lane = threadIdx.x & 63;
    const int qi   = threadIdx.x >> 6;
    const int R    = blockIdx.x * 64 + lane;      // global row in [0, BB*NN)
    const int b    = R / NN;
    const int col  = R - b * NN;

    const float* dp = degp + ((size_t)b * nslab) * NN + col;
    float a0 = 0.f;
    for (int s = qi; s < nslab; s += 4) a0 += dp[(size_t)s * NN];
    dred[qi][lane] = a0;
    __syncthreads();

    if (qi == 0) {
        const float deg = dred[0][lane] + dred[1][lane] + dred[2][lane] + dred[3][lane];
        const float inv = 1.0f / deg;
        float acc = 0.0f;
#pragma unroll
        for (int d = 0; d < 3; ++d) {
            const float c = q[(size_t)R * 3 + d] - neigh[(size_t)R * 3 + d] * inv;
            acc += c * c;
        }
#pragma unroll
        for (int sft = 32; sft > 0; sft >>= 1) acc += __shfl_down(acc, sft, 64);
        if (lane == 0) atomicAdd(out, acc);
    }
}

extern "C" void kernel_launch(void* const* d_in, const int* in_sizes, int n_in,
                              void* d_out, int out_size, void* d_ws, size_t ws_size,
                              hipStream_t stream) {
    const float* pred1 = (const float*)d_in[0];
    const float* pred2 = (const float*)d_in[1];
    const float* A     = (const float*)d_in[2];
    float* out = (float*)d_out;

    float* q     = (float*)d_ws;
    float* neigh = q + (size_t)BB * NN * 3;
    float* degp  = neigh + (size_t)BB * NN * 3;

    const size_t need_partial =
        ((size_t)BB * NN * 3 * 2 + (size_t)BB * NRB * NN) * sizeof(float);
    const int atomic_mode = (ws_size < need_partial) ? 1 : 0;
    const int nslab = atomic_mode ? 1 : NRB;

    {
        const int total = BB * NN * 3;
        k_init<<<(total + 255) / 256, 256, 0, stream>>>(pred1, pred2, q, degp, out,
                                                        atomic_mode);
    }
    k_main<<<BB * NRB, TPB, 0, stream>>>(A, q, neigh, degp, atomic_mode);
    k_final<<<(BB * NN) / 64, 256, 0, stream>>>(q, neigh, degp, nslab, out);
}

// Round 4
// 152.162 us; speedup vs baseline: 1.3521x; 1.3521x over previous
//
#include <hip/hip_runtime.h>

#define BB 8
#define NN 4096
#define TPB 1024
#define NWAVE 16                 // waves per block; each owns a 256-col window
#define TI 32                    // rows per block
#define NRB (NN / TI)            // 128 row-blocks per batch

// ws layout (floats):
//   q:     [BB*NN*3]                 offset 0
//   neigh: [BB*NN*3]                 offset 98304
//   degp:  [BB*NRB*NN] (or [BB*NN])  offset 196608
// partial mode total ~17.6 MB

__global__ __launch_bounds__(256) void k_init(const float* __restrict__ p1,
                                              const float* __restrict__ p2,
                                              float* __restrict__ q,
                                              float* __restrict__ deg_atomic,
                                              float* __restrict__ out,
                                              int atomic_mode) {
    int i = blockIdx.x * 256 + threadIdx.x;
    if (i < BB * NN * 3) q[i] = p2[i] - p1[i];
    if (atomic_mode && i < BB * NN) deg_atomic[i] = 0.0f;
    if (i == 0) out[0] = 0.0f;
}

__global__ __launch_bounds__(TPB, 8) void k_main(const float* __restrict__ A,
                                                 const float* __restrict__ q,
                                                 float* __restrict__ neigh,
                                                 float* __restrict__ degp,
                                                 int atomic_mode) {
    __shared__ float lds_n[TI][NWAVE][4];   // 8 KiB: per-(row,wave) dot partials

    const int tid  = threadIdx.x;
    const int lane = tid & 63;
    const int w    = tid >> 6;
    const int b    = blockIdx.x / NRB;
    const int rb   = blockIdx.x % NRB;
    const int ro   = rb * TI;
    const int jc   = w * 256 + lane * 4;    // this lane's 4 fixed columns

    const float* Ab = A + (size_t)b * NN * NN;
    const float* qb = q + (size_t)b * NN * 3;

    // q for the 4 fixed columns: 12 floats, loaded once
    const float4 q0 = *(const float4*)(qb + (size_t)jc * 3);
    const float4 q1 = *(const float4*)(qb + (size_t)jc * 3 + 4);
    const float4 q2 = *(const float4*)(qb + (size_t)jc * 3 + 8);
    // col0=(q0.x,q0.y,q0.z) col1=(q0.w,q1.x,q1.y) col2=(q1.z,q1.w,q2.x) col3=(q2.y,q2.z,q2.w)

    float dg0 = 0.f, dg1 = 0.f, dg2 = 0.f, dg3 = 0.f;
    const float* base = Ab + (size_t)ro * NN + jc;

#pragma unroll 2
    for (int r = 0; r < TI; ++r) {
        const float4 a = *(const float4*)(base + (size_t)r * NN);
        dg0 += a.x; dg1 += a.y; dg2 += a.z; dg3 += a.w;
        float n0 = a.x * q0.x + a.y * q0.w + a.z * q1.z + a.w * q2.y;
        float n1 = a.x * q0.y + a.y * q1.x + a.z * q1.w + a.w * q2.z;
        float n2 = a.x * q0.z + a.y * q1.y + a.z * q2.x + a.w * q2.w;
        // full-wave butterfly: every lane ends with the window's dot partial
#pragma unroll
        for (int s = 1; s < 64; s <<= 1) {
            n0 += __shfl_xor(n0, s, 64);
            n1 += __shfl_xor(n1, s, 64);
            n2 += __shfl_xor(n2, s, 64);
        }
        if (lane == 0) {
            lds_n[r][w][0] = n0;
            lds_n[r][w][1] = n1;
            lds_n[r][w][2] = n2;
        }
    }

    // flush deg partials: one coalesced float4 store per lane
    if (atomic_mode) {
        float* dgp = degp + (size_t)b * NN + jc;
        atomicAdd(&dgp[0], dg0);
        atomicAdd(&dgp[1], dg1);
        atomicAdd(&dgp[2], dg2);
        atomicAdd(&dgp[3], dg3);
    } else {
        float* dgp = degp + ((size_t)b * NRB + rb) * NN + jc;
        *(float4*)dgp = make_float4(dg0, dg1, dg2, dg3);
    }

    __syncthreads();
    // combine neigh partials across the 16 waves: 96 outputs
    if (tid < TI * 3) {
        const int r = tid / 3;
        const int d = tid - r * 3;
        float s = 0.f;
#pragma unroll
        for (int ww = 0; ww < NWAVE; ++ww) s += lds_n[r][ww][d];
        neigh[((size_t)b * NN + ro) * 3 + tid] = s;
    }
}

// 512 blocks x 256 threads; block handles 64 rows, each of the 4 waves sums a
// quarter of the slabs, LDS-combine, then wave 0 finishes the loss.
__global__ __launch_bounds__(256) void k_final(const float* __restrict__ q,
                                               const float* __restrict__ neigh,
                                               const float* __restrict__ degp,
                                               int nslab,
                                               float* __restrict__ out) {
    __shared__ float dred[4][64];
    const int lane = threadIdx.x & 63;
    const int qi   = threadIdx.x >> 6;
    const int R    = blockIdx.x * 64 + lane;      // global row in [0, BB*NN)
    const int b    = R / NN;
    const int col  = R - b * NN;

    const float* dp = degp + ((size_t)b * nslab) * NN + col;
    float a0 = 0.f;
    for (int s = qi; s < nslab; s += 4) a0 += dp[(size_t)s * NN];
    dred[qi][lane] = a0;
    __syncthreads();

    if (qi == 0) {
        const float deg = dred[0][lane] + dred[1][lane] + dred[2][lane] + dred[3][lane];
        const float inv = 1.0f / deg;
        float acc = 0.0f;
#pragma unroll
        for (int d = 0; d < 3; ++d) {
            const float c = q[(size_t)R * 3 + d] - neigh[(size_t)R * 3 + d] * inv;
            acc += c * c;
        }
#pragma unroll
        for (int sft = 32; sft > 0; sft >>= 1) acc += __shfl_down(acc, sft, 64);
        if (lane == 0) atomicAdd(out, acc);
    }
}

extern "C" void kernel_launch(void* const* d_in, const int* in_sizes, int n_in,
                              void* d_out, int out_size, void* d_ws, size_t ws_size,
                              hipStream_t stream) {
    const float* pred1 = (const float*)d_in[0];
    const float* pred2 = (const float*)d_in[1];
    const float* A     = (const float*)d_in[2];
    float* out = (float*)d_out;

    float* q     = (float*)d_ws;
    float* neigh = q + (size_t)BB * NN * 3;
    float* degp  = neigh + (size_t)BB * NN * 3;

    const size_t need_partial =
        ((size_t)BB * NN * 3 * 2 + (size_t)BB * NRB * NN) * sizeof(float);
    const int atomic_mode = (ws_size < need_partial) ? 1 : 0;
    const int nslab = atomic_mode ? 1 : NRB;

    {
        const int total = BB * NN * 3;
        k_init<<<(total + 255) / 256, 256, 0, stream>>>(pred1, pred2, q, degp, out,
                                                        atomic_mode);
    }
    k_main<<<BB * NRB, TPB, 0, stream>>>(A, q, neigh, degp, atomic_mode);
    k_final<<<(BB * NN) / 64, 256, 0, stream>>>(q, neigh, degp, nslab, out);
}